// Round 15
// baseline (487.995 us; speedup 1.0000x reference)
//
#include <hip/hip_runtime.h>
#include <math.h>

#define NN 50000
#define EE 800000
#define GG 64
#define HH 96
#define H2 192
#define INF 32
#define EDF 16
#define OUTF 128
#define EPS_GEN 1e-7f
#define EPS_BN 1e-5f
#define NPB 100     // nodes per pool block
#define NB_SCAN 49  // ceil(NN/1024)
#define NBH (256 * NB_SCAN)
#define BSCAN_PT 13  // ceil(NBH/1024)
#define LOG2E 1.44269504088896f
#define SHIFT2 28.85390081777927f  // 20*log2e
#define GRIDP 512    // persistent gemm grid (2 blocks/CU)
#define NT64 ((NN + 63) / 64)  // 782 row tiles
#define PROJ_GRID 1024  // persistent proj grid (4 blocks/CU)

typedef _Float16 f16;
typedef _Float16 f16x2 __attribute__((ext_vector_type(2)));
typedef _Float16 f16x8 __attribute__((ext_vector_type(8)));
typedef float f32x4 __attribute__((ext_vector_type(4)));

static inline size_t align256(size_t x) { return (x + 255) & ~(size_t)255; }

__device__ __forceinline__ float fdot2(f16x2 a, f16x2 b, float c) {
#if __has_builtin(__builtin_amdgcn_fdot2)
    return __builtin_amdgcn_fdot2(a, b, c, false);
#else
    return fmaf((float)a.x, (float)b.x, fmaf((float)a.y, (float)b.y, c));
#endif
}

__device__ __forceinline__ float exp2fast(float x) {
#if __has_builtin(__builtin_amdgcn_exp2f)
    return __builtin_amdgcn_exp2f(x);
#else
    return exp2f(x);
#endif
}

union W8 { float4 f[2]; f16x2 h[8]; };
union EAu { float4 f; f16x2 h[4]; };
union XUu { float2 f; f16x2 h[2]; };

__device__ __forceinline__ void agg_step(const EAu& e0, const EAu& e1, const XUu& xu,
                                         const W8* w, float* num, float* den) {
    float xv[4] = {(float)xu.h[0].x, (float)xu.h[0].y, (float)xu.h[1].x, (float)xu.h[1].y};
    #pragma unroll
    for (int cc = 0; cc < 4; ++cc) {
        float acc = 0.f;
        #pragma unroll
        for (int k = 0; k < 4; ++k) acc = fdot2(e0.h[k], w[cc].h[k], acc);
        #pragma unroll
        for (int k = 0; k < 4; ++k) acc = fdot2(e1.h[k], w[cc].h[4 + k], acc);
        float msg = fmaxf(xv[cc] + acc, 0.f) + EPS_GEN;
        float p = exp2fast(fmaf(msg, LOG2E, -SHIFT2));
        den[cc] += p;
        num[cc] = fmaf(msg, p, num[cc]);
    }
}

// ---------------- CSR build ----------------

// histogram + per-edge rank capture (atomic return value = edge's rank within its dst)
__global__ __launch_bounds__(256) void hist_kernel(const int* __restrict__ dst,
                                                   int* __restrict__ deg,
                                                   int* __restrict__ rank) {
    int e = blockIdx.x * 256 + threadIdx.x;
    if (e >= EE) return;
    rank[e] = atomicAdd(&deg[dst[e]], 1);
}

// block-local exclusive scan + per-block totals; also per-block degree histogram
// (bucket = 255 - clamp(deg) so high-degree nodes sort FIRST -> LPT scheduling)
__global__ __launch_bounds__(1024) void scan1_kernel(const int* __restrict__ deg,
                                                     int* __restrict__ offs,
                                                     int* __restrict__ bsum,
                                                     int* __restrict__ bhist) {
    __shared__ int ws[16];
    __shared__ int lh[256];
    int tid = threadIdx.x, lane = tid & 63, w = tid >> 6;
    if (tid < 256) lh[tid] = 0;
    int i = blockIdx.x * 1024 + tid;
    int v = (i < NN) ? deg[i] : 0;
    __syncthreads();
    if (i < NN) {
        int b = 255 - (v > 255 ? 255 : v);
        atomicAdd(&lh[b], 1);
    }
    int x = v;
    #pragma unroll
    for (int off = 1; off < 64; off <<= 1) {
        int y = __shfl_up(x, off, 64);
        if (lane >= off) x += y;
    }
    if (lane == 63) ws[w] = x;
    __syncthreads();
    int wpre = 0;
    for (int j = 0; j < w; ++j) wpre += ws[j];
    if (i < NN) offs[i] = wpre + x - v;
    if (tid == 1023) bsum[blockIdx.x] = wpre + x;
    if (tid < 256) bhist[tid * NB_SCAN + blockIdx.x] = lh[tid];
}

// merged: fast bhist exclusive scan (local-13 + one block scan) + bsum scan + pool zero
__global__ __launch_bounds__(1024) void bscan_kernel(int* __restrict__ bhist,
                                                     int* __restrict__ bsum,
                                                     float* __restrict__ pool) {
    __shared__ int ws[16];
    int tid = threadIdx.x, lane = tid & 63, w = tid >> 6;
    for (int i = tid; i < GG * HH; i += 1024) pool[i] = 0.f;
    if (tid < 64) {
        int v = (tid < NB_SCAN) ? bsum[tid] : 0;
        int x = v;
        #pragma unroll
        for (int off = 1; off < 64; off <<= 1) {
            int y = __shfl_up(x, off, 64);
            if (lane >= off) x += y;
        }
        if (tid < NB_SCAN) bsum[tid] = x - v;
    }
    int base = tid * BSCAN_PT;
    int loc[BSCAN_PT];
    int s = 0;
    #pragma unroll
    for (int i = 0; i < BSCAN_PT; ++i) {
        int idx = base + i;
        int v = (idx < NBH) ? bhist[idx] : 0;
        loc[i] = s;
        s += v;
    }
    int x = s;
    #pragma unroll
    for (int off = 1; off < 64; off <<= 1) {
        int y = __shfl_up(x, off, 64);
        if (lane >= off) x += y;
    }
    if (lane == 63) ws[w] = x;
    __syncthreads();
    int wpre = 0;
    for (int j = 0; j < w; ++j) wpre += ws[j];
    int pre = wpre + x - s;  // exclusive prefix of this thread's chunk
    #pragma unroll
    for (int i = 0; i < BSCAN_PT; ++i) {
        int idx = base + i;
        if (idx < NBH) bhist[idx] = pre + loc[i];
    }
}

// merged: offs finalize + degree-sorted permutation (no global atomics)
__global__ __launch_bounds__(1024) void finsort_kernel(int* __restrict__ offs,
                                                       const int* __restrict__ bsum,
                                                       const int* __restrict__ deg,
                                                       const int* __restrict__ bhist,
                                                       int* __restrict__ perm) {
    __shared__ int cnt[256];
    int tid = threadIdx.x;
    if (tid < 256) cnt[tid] = 0;
    __syncthreads();
    int n = blockIdx.x * 1024 + tid;
    if (n < NN) {
        offs[n] += bsum[blockIdx.x];
        int d = deg[n];
        int b = 255 - (d > 255 ? 255 : d);
        int rank = atomicAdd(&cnt[b], 1);
        perm[bhist[b * NB_SCAN + blockIdx.x] + rank] = n;
    }
    if (n == NN) offs[NN] = EE;
}

// scatter (NO atomics): 64B-slot csrea -> FULL-LINE writes, no L2 RMW fetch.
// slot layout: [32B f16 attrs][32B pad]; csr_src stays a separate array (feeds
// agg's prefetch pipeline one iteration early).
__global__ __launch_bounds__(256) void scatter_kernel(const int* __restrict__ src,
                                                      const int* __restrict__ dst,
                                                      const int* __restrict__ offs,
                                                      const int* __restrict__ rank,
                                                      const float* __restrict__ eattr,
                                                      int* __restrict__ csr_src,
                                                      float4* __restrict__ csrea) {
    int e = blockIdx.x * 256 + threadIdx.x;
    if (e >= EE) return;
    int d = dst[e];
    int slot = offs[d] + rank[e];
    csr_src[slot] = src[e] * (HH * 2);  // byte offset into f16 hidden-state array
    const float4* ep = (const float4*)(eattr + (size_t)e * EDF);
    float4 v0 = ep[0], v1 = ep[1], v2 = ep[2], v3 = ep[3];
    union { f16x2 h[4]; float4 f; } a, b;
    a.h[0] = f16x2{(f16)v0.x, (f16)v0.y};
    a.h[1] = f16x2{(f16)v0.z, (f16)v0.w};
    a.h[2] = f16x2{(f16)v1.x, (f16)v1.y};
    a.h[3] = f16x2{(f16)v1.z, (f16)v1.w};
    b.h[0] = f16x2{(f16)v2.x, (f16)v2.y};
    b.h[1] = f16x2{(f16)v2.z, (f16)v2.w};
    b.h[2] = f16x2{(f16)v3.x, (f16)v3.y};
    b.h[3] = f16x2{(f16)v3.z, (f16)v3.w};
    float4* outp = csrea + (size_t)slot * 4;
    outp[0] = a.f;
    outp[1] = b.f;
    outp[2] = float4{0.f, 0.f, 0.f, 0.f};  // pad: completes the 64B line
    outp[3] = float4{0.f, 0.f, 0.f, 0.f};
}

// ---- weight prep + csr pad zeroing ----
__global__ __launch_bounds__(256) void wprep_kernel(
    const float* __restrict__ we0, const float* __restrict__ we1, const float* __restrict__ we2,
    const float* __restrict__ m10, const float* __restrict__ m11, const float* __restrict__ m12,
    const float* __restrict__ m20, const float* __restrict__ m21, const float* __restrict__ m22,
    f16* __restrict__ wte, f16* __restrict__ wt1, f16* __restrict__ wt2,
    int* __restrict__ csr_src) {
    int idx = blockIdx.x * 256 + threadIdx.x;
    if (idx < 8) csr_src[EE + idx] = 0;  // pads: agg prefetch overruns gather node 0
    if (idx < 4608) {
        const float* w = (idx < 1536) ? we0 : ((idx < 3072) ? we1 : we2);
        int r = idx % 1536, c = r / EDF, k = r % EDF;
        wte[idx] = (f16)w[k * HH + c];
    } else if (idx < 4608 + 3 * 18432) {
        int m = idx - 4608;
        const float* w = (m < 18432) ? m10 : ((m < 36864) ? m11 : m12);
        int r = m % 18432, j = r / HH, k = r % HH;  // [192][96]
        wt1[m] = (f16)w[k * H2 + j];
    } else if (idx < 4608 + 6 * 18432) {
        int m = idx - 4608 - 3 * 18432;
        const float* w = (m < 18432) ? m20 : ((m < 36864) ? m21 : m22);
        int r = m % 18432, j = r / H2, k = r % H2;  // [96][192]
        wt2[m] = (f16)w[k * HH + j];
    }
}

// ------- layer-1 input projections (f16 out), PERSISTENT: stage weights once -------

__global__ __launch_bounds__(256) void proj_kernel(const float* __restrict__ x,
                                                   const float* __restrict__ ws,
                                                   const float* __restrict__ wd,
                                                   f16* __restrict__ xs,
                                                   f16* __restrict__ xd) {
    __shared__ float Ws[INF * HH], Wd[INF * HH];
    int tid = threadIdx.x;
    for (int i = tid; i < INF * HH; i += 256) { Ws[i] = ws[i]; Wd[i] = wd[i]; }
    __syncthreads();
    for (int gid = blockIdx.x * 256 + tid; gid < NN * HH; gid += PROJ_GRID * 256) {
        int n = gid / HH, c = gid % HH;
        const float* xr = x + (size_t)n * INF;
        float as = 0.f, ad = 0.f;
        #pragma unroll
        for (int k = 0; k < INF; ++k) {
            float xv = xr[k];
            as = fmaf(xv, Ws[k * HH + c], as);
            ad = fmaf(xv, Wd[k * HH + c], ad);
        }
        xs[gid] = (f16)as;
        xd[gid] = (f16)ad;
    }
}

// ---- GENConv softmax aggregation: LPT-sorted, unroll-3 rotation, 64B-slot reads ----

#define AGG_LOAD(E0, E1, XU, JJ, SO)                                     \
    E0.f = csrea[(size_t)(JJ) * 4];                                      \
    E1.f = csrea[(size_t)(JJ) * 4 + 1];                                  \
    XU.f = *(const float2*)(xsrcb + (size_t)(unsigned)(SO) + c0 * 2);

__global__ __launch_bounds__(192) void agg_kernel(const f16* __restrict__ xsrc,
                                                  const f16* __restrict__ xdst,
                                                  const float4* __restrict__ csrea,
                                                  const f16* __restrict__ wt,
                                                  const int* __restrict__ offs,
                                                  const int* __restrict__ csr_src,
                                                  const int* __restrict__ perm,
                                                  float* __restrict__ stats,
                                                  f16* __restrict__ hpre) {
    int tid = threadIdx.x;
    if (blockIdx.x == 0) {  // fold BN-stats zeroing (consumed by gemm1/gemm2 after us)
        for (int t = tid; t < 576; t += 192) stats[t] = 0.f;
    }
    int idx = blockIdx.x * 8 + tid / 24;
    if (idx >= NN) return;
    int node = perm[idx];
    int cg = tid % 24, c0 = cg * 4;
    const char* xsrcb = (const char*)xsrc;
    W8 w[4];
    #pragma unroll
    for (int cc = 0; cc < 4; ++cc) {
        const float4* wp = (const float4*)(wt + (c0 + cc) * EDF);
        w[cc].f[0] = wp[0];
        w[cc].f[1] = wp[1];
    }
    XUu xd;
    xd.f = *(const float2*)(xdst + (size_t)node * HH + c0);
    int s0 = offs[node], s1 = offs[node + 1];
    float num[4] = {0.f, 0.f, 0.f, 0.f}, den[4] = {0.f, 0.f, 0.f, 0.f};
    if (s0 < s1) {
        int last = s1 - 1;
        EAu eA0, eA1, eB0, eB1, eC0, eC1;
        XUu xA, xB, xC;
        int sA = csr_src[s0], sB = csr_src[s0 + 1], sC = csr_src[s0 + 2];
        AGG_LOAD(eA0, eA1, xA, s0, sA)
        AGG_LOAD(eB0, eB1, xB, s0 + 1, sB)
        AGG_LOAD(eC0, eC1, xC, s0 + 2, sC)
        int sD = csr_src[s0 + 3], sE = csr_src[s0 + 4], sF = csr_src[s0 + 5];
        for (int j = s0; j < s1; j += 3) {
            // slot A: compute (always valid), then reload for j+3
            __builtin_amdgcn_s_setprio(1);
            agg_step(eA0, eA1, xA, w, num, den);
            __builtin_amdgcn_s_setprio(0);
            AGG_LOAD(eA0, eA1, xA, j + 3, sD)
            sD = csr_src[j + 6];
            // slot B
            if (j + 1 <= last) {
                __builtin_amdgcn_s_setprio(1);
                agg_step(eB0, eB1, xB, w, num, den);
                __builtin_amdgcn_s_setprio(0);
            }
            AGG_LOAD(eB0, eB1, xB, j + 4, sE)
            sE = csr_src[j + 7];
            // slot C
            if (j + 2 <= last) {
                __builtin_amdgcn_s_setprio(1);
                agg_step(eC0, eC1, xC, w, num, den);
                __builtin_amdgcn_s_setprio(0);
            }
            AGG_LOAD(eC0, eC1, xC, j + 5, sF)
            sF = csr_src[j + 8];
        }
    }
    float xdv[4] = {(float)xd.h[0].x, (float)xd.h[0].y, (float)xd.h[1].x, (float)xd.h[1].y};
    float r0 = (den[0] > 0.f) ? num[0] / den[0] : 0.f;
    float r1 = (den[1] > 0.f) ? num[1] / den[1] : 0.f;
    float r2 = (den[2] > 0.f) ? num[2] / den[2] : 0.f;
    float r3 = (den[3] > 0.f) ? num[3] / den[3] : 0.f;
    union { float2 f; f16x2 h[2]; } o;
    o.h[0] = f16x2{(f16)(r0 + xdv[0]), (f16)(r1 + xdv[1])};
    o.h[1] = f16x2{(f16)(r2 + xdv[2]), (f16)(r3 + xdv[3])};
    *(float2*)(hpre + (size_t)node * HH + c0) = o.f;
}

// -- gemm1 (MFMA, persistent): T = HP @ mw1 [N,96]x[96,192]; W staged once; stats in LDS --
#define LDA1 104  // f16 units, 16B-aligned rows, breaks bank aliasing

__global__ __launch_bounds__(256) void gemm1_kernel(const f16* __restrict__ A,
                                                    const f16* __restrict__ Wt,
                                                    f16* __restrict__ T,
                                                    float* __restrict__ colsum,
                                                    float* __restrict__ colsumsq) {
    __shared__ f16 Al[64 * LDA1];
    __shared__ f16 Wl[192 * LDA1];
    __shared__ float red[H2 * 2];
    int tid = threadIdx.x;
    for (int v = tid; v < 192 * 12; v += 256) {
        int r = v / 12, c8 = (v % 12) * 8;
        *(float4*)(Wl + r * LDA1 + c8) = *(const float4*)(Wt + r * HH + c8);
    }
    for (int t = tid; t < H2 * 2; t += 256) red[t] = 0.f;
    __syncthreads();
    int wv = tid >> 6, l = tid & 63, lr = l & 15, lg = l >> 4;
    int i0 = wv * 16;
    for (int tile = blockIdx.x; tile < NT64; tile += GRIDP) {
        int n0 = tile * 64;
        for (int v = tid; v < 64 * 12; v += 256) {
            int r = v / 12, c8 = (v % 12) * 8;
            float4 d = {0.f, 0.f, 0.f, 0.f};
            if (n0 + r < NN) d = *(const float4*)(A + (size_t)(n0 + r) * HH + c8);
            *(float4*)(Al + r * LDA1 + c8) = d;
        }
        __syncthreads();
        f32x4 acc[12];
        #pragma unroll
        for (int t = 0; t < 12; ++t) acc[t] = (f32x4){0.f, 0.f, 0.f, 0.f};
        #pragma unroll
        for (int ks = 0; ks < 3; ++ks) {
            int k0 = ks * 32 + lg * 8;
            f16x8 af = *(const f16x8*)(Al + (i0 + lr) * LDA1 + k0);
            #pragma unroll
            for (int t = 0; t < 12; ++t) {
                f16x8 bf = *(const f16x8*)(Wl + (t * 16 + lr) * LDA1 + k0);
                acc[t] = __builtin_amdgcn_mfma_f32_16x16x32_f16(af, bf, acc[t], 0, 0, 0);
            }
        }
        #pragma unroll
        for (int t = 0; t < 12; ++t) {
            int col = t * 16 + lr;
            float s = 0.f, q = 0.f;
            #pragma unroll
            for (int rr = 0; rr < 4; ++rr) {
                int row = n0 + i0 + lg * 4 + rr;
                float v = acc[t][rr];
                if (row < NN) {
                    T[(size_t)row * H2 + col] = (f16)v;
                    s += v;
                    q = fmaf(v, v, q);
                }
            }
            s += __shfl_xor(s, 16); s += __shfl_xor(s, 32);
            q += __shfl_xor(q, 16); q += __shfl_xor(q, 32);
            if (lg == 0) { atomicAdd(&red[col], s); atomicAdd(&red[H2 + col], q); }
        }
        __syncthreads();  // red complete + Al free before next tile
    }
    if (tid < H2) {
        atomicAdd(&colsum[tid], red[tid]);
        atomicAdd(&colsumsq[tid], red[H2 + tid]);
    }
}

// -- gemm2 (MFMA, persistent): U = relu(bn1(T)) @ mw2 [N,192]x[192,96], BN fused --
#define LDA2 200

__global__ __launch_bounds__(256) void gemm2_kernel(const f16* __restrict__ T,
                                                    const f16* __restrict__ Wt,
                                                    const float* __restrict__ cs1,
                                                    const float* __restrict__ cq1,
                                                    const float* __restrict__ g1,
                                                    const float* __restrict__ b1,
                                                    f16* __restrict__ U,
                                                    float* __restrict__ colsum,
                                                    float* __restrict__ colsumsq) {
    __shared__ f16 Al[64 * LDA2];
    __shared__ f16 Wl[96 * LDA2];
    __shared__ float ab[H2 * 2];
    __shared__ float red[HH * 2];
    int tid = threadIdx.x;
    if (tid < H2) {
        const float invN = 1.f / (float)NN;
        float mu = cs1[tid] * invN;
        float var = fmaxf(cq1[tid] * invN - mu * mu, 0.f);
        float a = g1[tid] * rsqrtf(var + EPS_BN);
        ab[tid] = a;
        ab[H2 + tid] = b1[tid] - mu * a;
    }
    if (tid < HH * 2) red[tid] = 0.f;
    for (int v = tid; v < 96 * 24; v += 256) {
        int r = v / 24, c8 = (v % 24) * 8;
        *(float4*)(Wl + r * LDA2 + c8) = *(const float4*)(Wt + r * H2 + c8);
    }
    __syncthreads();
    int wv = tid >> 6, l = tid & 63, lr = l & 15, lg = l >> 4;
    int i0 = wv * 16;
    for (int tile = blockIdx.x; tile < NT64; tile += GRIDP) {
        int n0 = tile * 64;
        for (int v = tid; v < 64 * 24; v += 256) {
            int r = v / 24, c8 = (v % 24) * 8;
            float4 dd = {0.f, 0.f, 0.f, 0.f};
            if (n0 + r < NN) {
                union { float4 f; f16x2 h[4]; } u, o;
                u.f = *(const float4*)(T + (size_t)(n0 + r) * H2 + c8);
                #pragma unroll
                for (int p = 0; p < 4; ++p) {
                    float x0 = fmaxf(fmaf((float)u.h[p].x, ab[c8 + 2 * p], ab[H2 + c8 + 2 * p]), 0.f);
                    float x1 = fmaxf(fmaf((float)u.h[p].y, ab[c8 + 2 * p + 1], ab[H2 + c8 + 2 * p + 1]), 0.f);
                    o.h[p] = f16x2{(f16)x0, (f16)x1};
                }
                dd = o.f;
            }
            *(float4*)(Al + r * LDA2 + c8) = dd;
        }
        __syncthreads();
        f32x4 acc[6];
        #pragma unroll
        for (int t = 0; t < 6; ++t) acc[t] = (f32x4){0.f, 0.f, 0.f, 0.f};
        #pragma unroll
        for (int ks = 0; ks < 6; ++ks) {
            int k0 = ks * 32 + lg * 8;
            f16x8 af = *(const f16x8*)(Al + (i0 + lr) * LDA2 + k0);
            #pragma unroll
            for (int t = 0; t < 6; ++t) {
                f16x8 bf = *(const f16x8*)(Wl + (t * 16 + lr) * LDA2 + k0);
                acc[t] = __builtin_amdgcn_mfma_f32_16x16x32_f16(af, bf, acc[t], 0, 0, 0);
            }
        }
        #pragma unroll
        for (int t = 0; t < 6; ++t) {
            int col = t * 16 + lr;
            float s = 0.f, q = 0.f;
            #pragma unroll
            for (int rr = 0; rr < 4; ++rr) {
                int row = n0 + i0 + lg * 4 + rr;
                float v = acc[t][rr];
                if (row < NN) {
                    U[(size_t)row * HH + col] = (f16)v;
                    s += v;
                    q = fmaf(v, v, q);
                }
            }
            s += __shfl_xor(s, 16); s += __shfl_xor(s, 32);
            q += __shfl_xor(q, 16); q += __shfl_xor(q, 32);
            if (lg == 0) { atomicAdd(&red[col], s); atomicAdd(&red[HH + col], q); }
        }
        __syncthreads();
    }
    if (tid < HH) {
        atomicAdd(&colsum[tid], red[tid]);
        atomicAdd(&colsumsq[tid], red[HH + tid]);
    }
}

// ---------------- h = relu(bn_out(u)), BN finalize fused ----------------

__global__ __launch_bounds__(256) void elem_kernel(const f16* __restrict__ U,
                                                   const float* __restrict__ cs2,
                                                   const float* __restrict__ cq2,
                                                   const float* __restrict__ g2,
                                                   const float* __restrict__ b2,
                                                   f16* __restrict__ Hout) {
    __shared__ float ab[HH * 2];
    int tid = threadIdx.x;
    if (tid < HH) {
        const float invN = 1.f / (float)NN;
        float mu = cs2[tid] * invN;
        float var = fmaxf(cq2[tid] * invN - mu * mu, 0.f);
        float a = g2[tid] * rsqrtf(var + EPS_BN);
        ab[tid] = a;
        ab[HH + tid] = b2[tid] - mu * a;
    }
    __syncthreads();
    int i = blockIdx.x * 256 + tid;
    if (i >= NN * HH / 8) return;
    union { float4 f; f16x2 h[4]; } u, o;
    u.f = ((const float4*)U)[i];
    int k = (i % 12) * 8;
    #pragma unroll
    for (int p = 0; p < 4; ++p) {
        float x0 = fmaxf(fmaf((float)u.h[p].x, ab[k + 2 * p], ab[HH + k + 2 * p]), 0.f);
        float x1 = fmaxf(fmaf((float)u.h[p].y, ab[k + 2 * p + 1], ab[HH + k + 2 * p + 1]), 0.f);
        o.h[p] = f16x2{(f16)x0, (f16)x1};
    }
    ((float4*)Hout)[i] = o.f;
}

// ------- mean-pool with fused final BN+relu (last layer), segmented accumulation -------

__global__ __launch_bounds__(192) void pool_bn_kernel(const f16* __restrict__ U,
                                                      const float* __restrict__ cs2,
                                                      const float* __restrict__ cq2,
                                                      const float* __restrict__ g2,
                                                      const float* __restrict__ b2,
                                                      const int* __restrict__ batch,
                                                      float* __restrict__ pool) {
    __shared__ float ab[HH * 2];
    int tid = threadIdx.x;
    if (tid < HH) {
        const float invN = 1.f / (float)NN;
        float mu = cs2[tid] * invN;
        float var = fmaxf(cq2[tid] * invN - mu * mu, 0.f);
        float a = g2[tid] * rsqrtf(var + EPS_BN);
        ab[tid] = a;
        ab[HH + tid] = b2[tid] - mu * a;
    }
    __syncthreads();
    int n0 = blockIdx.x * NPB;
    int n1 = (n0 + NPB < NN) ? n0 + NPB : NN;
    int c = tid % HH;
    int h = tid / HH;
    float a_ = ab[c], b_ = ab[HH + c];
    float acc = 0.f;
    int gcur = -1;
    for (int n = n0 + h; n < n1; n += 2) {
        int g = batch[n];
        if (g != gcur) {
            if (gcur >= 0) atomicAdd(&pool[gcur * HH + c], acc);
            acc = 0.f;
            gcur = g;
        }
        acc += fmaxf(fmaf((float)U[(size_t)n * HH + c], a_, b_), 0.f);
    }
    if (gcur >= 0) atomicAdd(&pool[gcur * HH + c], acc);
}

// final linear; per-graph count via binary search (fused, uniform per block)
__global__ __launch_bounds__(128) void out_kernel(const float* __restrict__ pool,
                                                  const int* __restrict__ batch,
                                                  const float* __restrict__ lw,
                                                  const float* __restrict__ lb,
                                                  float* __restrict__ out) {
    int g = blockIdx.x, o = threadIdx.x;
    int lo = 0, hi = NN;
    while (lo < hi) { int mid = (lo + hi) >> 1; if (batch[mid] < g) lo = mid + 1; else hi = mid; }
    int s = lo;
    lo = 0; hi = NN;
    while (lo < hi) { int mid = (lo + hi) >> 1; if (batch[mid] < g + 1) lo = mid + 1; else hi = mid; }
    float inv = 1.f / fmaxf((float)(lo - s), 1.f);
    float acc = lb[o];
    for (int c = 0; c < HH; ++c) acc = fmaf(pool[g * HH + c] * inv, lw[c * OUTF + o], acc);
    out[(size_t)g * OUTF + o] = acc;
}

// ---------------- host ----------------

extern "C" void kernel_launch(void* const* d_in, const int* in_sizes, int n_in,
                              void* d_out, int out_size, void* d_ws, size_t ws_size,
                              hipStream_t stream) {
    const float* x = (const float*)d_in[0];
    const float* eattr = (const float*)d_in[1];
    const int* eidx = (const int*)d_in[2];
    const int* batch = (const int*)d_in[3];
    const float* w_src1 = (const float*)d_in[4];
    const float* w_dst1 = (const float*)d_in[5];
    const float* w_e[3] = {(const float*)d_in[6], (const float*)d_in[13], (const float*)d_in[20]};
    const float* mw1[3] = {(const float*)d_in[7], (const float*)d_in[14], (const float*)d_in[21]};
    const float* mg[3] = {(const float*)d_in[8], (const float*)d_in[15], (const float*)d_in[22]};
    const float* mb[3] = {(const float*)d_in[9], (const float*)d_in[16], (const float*)d_in[23]};
    const float* mw2[3] = {(const float*)d_in[10], (const float*)d_in[17], (const float*)d_in[24]};
    const float* bng[3] = {(const float*)d_in[11], (const float*)d_in[18], (const float*)d_in[25]};
    const float* bnb[3] = {(const float*)d_in[12], (const float*)d_in[19], (const float*)d_in[26]};
    const float* lin_w = (const float*)d_in[27];
    const float* lin_b = (const float*)d_in[28];
    float* out = (float*)d_out;

    const int* src = eidx;
    const int* dst = eidx + EE;

    // ---- workspace layout ----
    char* base = (char*)d_ws;
    size_t off = 0;
    int* deg = (int*)(base + off); off = align256(off + (size_t)NN * 4);
    int* offs = (int*)(base + off); off = align256(off + (size_t)(NN + 1) * 4);
    int* bsum = (int*)(base + off); off = align256(off + (size_t)NB_SCAN * 4);
    int* bhist = (int*)(base + off); off = align256(off + (size_t)NBH * 4);
    int* perm = (int*)(base + off); off = align256(off + (size_t)NN * 4);
    int* csr_src = (int*)(base + off); off = align256(off + (size_t)(EE + 8) * 4);
    float* stats = (float*)(base + off); off = align256(off + 576 * 4);
    float* colsum1 = stats;            // 192
    float* colsumsq1 = stats + 192;    // 192
    float* colsum2 = stats + 384;      // 96
    float* colsumsq2 = stats + 480;    // 96
    float* pool = (float*)(base + off); off = align256(off + (size_t)GG * HH * 4);
    f16* wte = (f16*)(base + off); off = align256(off + (size_t)3 * 1536 * 2);
    f16* wt1 = (f16*)(base + off); off = align256(off + (size_t)3 * 18432 * 2);
    f16* wt2 = (f16*)(base + off); off = align256(off + (size_t)3 * 18432 * 2);
    f16* XS = (f16*)(base + off); off = align256(off + (size_t)NN * HH * 2);   // xs -> h
    f16* XD = (f16*)(base + off); off = align256(off + (size_t)NN * HH * 2);   // xd (layer1)
    f16* HP = (f16*)(base + off); off = align256(off + (size_t)NN * HH * 2);   // hpre -> U
    f16* T = (f16*)(base + off); off = align256(off + (size_t)NN * H2 * 2);
    float4* csrea = (float4*)(base + off); off = align256(off + (size_t)(EE + 8) * 64);
    int* rank = (int*)T;  // aliased: rank dead before first T write (gemm1 layer 0)
    (void)in_sizes; (void)n_in; (void)out_size; (void)ws_size;

    // ---- CSR build + LPT degree sort (atomic-free scatter via rank capture) ----
    hipMemsetAsync(deg, 0, (size_t)NN * 4, stream);
    hist_kernel<<<(EE + 255) / 256, 256, 0, stream>>>(dst, deg, rank);
    scan1_kernel<<<NB_SCAN, 1024, 0, stream>>>(deg, offs, bsum, bhist);
    bscan_kernel<<<1, 1024, 0, stream>>>(bhist, bsum, pool);
    finsort_kernel<<<NB_SCAN, 1024, 0, stream>>>(offs, bsum, deg, bhist, perm);
    scatter_kernel<<<(EE + 255) / 256, 256, 0, stream>>>(src, dst, offs, rank, eattr,
                                                         csr_src, csrea);
    wprep_kernel<<<(4608 + 6 * 18432 + 255) / 256, 256, 0, stream>>>(
        w_e[0], w_e[1], w_e[2], mw1[0], mw1[1], mw1[2], mw2[0], mw2[1], mw2[2],
        wte, wt1, wt2, csr_src);
    proj_kernel<<<PROJ_GRID, 256, 0, stream>>>(x, w_src1, w_dst1, XS, XD);

    // ---- 3 GENConv layers ----
    for (int l = 0; l < 3; ++l) {
        const f16* xdst = (l == 0) ? XD : XS;
        agg_kernel<<<(NN + 7) / 8, 192, 0, stream>>>(XS, xdst, csrea, wte + l * 1536, offs,
                                                     csr_src, perm, stats, HP);
        gemm1_kernel<<<GRIDP, 256, 0, stream>>>(HP, wt1 + l * 18432, T, colsum1, colsumsq1);
        gemm2_kernel<<<GRIDP, 256, 0, stream>>>(T, wt2 + l * 18432, colsum1, colsumsq1,
                                                mg[l], mb[l], HP, colsum2, colsumsq2);
        if (l < 2)
            elem_kernel<<<(NN * HH / 8 + 255) / 256, 256, 0, stream>>>(HP, colsum2, colsumsq2,
                                                                       bng[l], bnb[l], XS);
    }

    // ---- pooling (fused layer-3 BN+relu; pool zeroed in bscan) + final linear ----
    pool_bn_kernel<<<(NN + NPB - 1) / NPB, 192, 0, stream>>>(HP, colsum2, colsumsq2,
                                                             bng[2], bnb[2], batch, pool);
    out_kernel<<<GG, 128, 0, stream>>>(pool, batch, lin_w, lin_b, out);
}

// Round 16
// 484.389 us; speedup vs baseline: 1.0074x; 1.0074x over previous
//
#include <hip/hip_runtime.h>
#include <math.h>

#define NN 50000
#define EE 800000
#define GG 64
#define HH 96
#define H2 192
#define INF 32
#define EDF 16
#define OUTF 128
#define EPS_GEN 1e-7f
#define EPS_BN 1e-5f
#define NPB 100     // nodes per pool block
#define NB_SCAN 49  // ceil(NN/1024)
#define NBH (256 * NB_SCAN)
#define BSCAN_PT 13  // ceil(NBH/1024)
#define LOG2E 1.44269504088896f
#define SHIFT2 28.85390081777927f  // 20*log2e
#define GRIDP 512    // persistent gemm grid (2 blocks/CU)
#define NT64 ((NN + 63) / 64)  // 782 row tiles
#define PROJ_GRID 1024  // persistent proj grid (4 blocks/CU)
#define WPREP_N (4608 + 6 * 18432)  // 115200 weight-prep items

typedef _Float16 f16;
typedef _Float16 f16x2 __attribute__((ext_vector_type(2)));
typedef _Float16 f16x8 __attribute__((ext_vector_type(8)));
typedef float f32x4 __attribute__((ext_vector_type(4)));

static inline size_t align256(size_t x) { return (x + 255) & ~(size_t)255; }

__device__ __forceinline__ float fdot2(f16x2 a, f16x2 b, float c) {
#if __has_builtin(__builtin_amdgcn_fdot2)
    return __builtin_amdgcn_fdot2(a, b, c, false);
#else
    return fmaf((float)a.x, (float)b.x, fmaf((float)a.y, (float)b.y, c));
#endif
}

__device__ __forceinline__ float exp2fast(float x) {
#if __has_builtin(__builtin_amdgcn_exp2f)
    return __builtin_amdgcn_exp2f(x);
#else
    return exp2f(x);
#endif
}

union W8 { float4 f[2]; f16x2 h[8]; };
union EAu { float4 f; f16x2 h[4]; };
union XUu { float2 f; f16x2 h[2]; };

__device__ __forceinline__ void agg_step(const EAu& e0, const EAu& e1, const XUu& xu,
                                         const W8* w, float* num, float* den) {
    float xv[4] = {(float)xu.h[0].x, (float)xu.h[0].y, (float)xu.h[1].x, (float)xu.h[1].y};
    #pragma unroll
    for (int cc = 0; cc < 4; ++cc) {
        float acc = 0.f;
        #pragma unroll
        for (int k = 0; k < 4; ++k) acc = fdot2(e0.h[k], w[cc].h[k], acc);
        #pragma unroll
        for (int k = 0; k < 4; ++k) acc = fdot2(e1.h[k], w[cc].h[4 + k], acc);
        float msg = fmaxf(xv[cc] + acc, 0.f) + EPS_GEN;
        float p = exp2fast(fmaf(msg, LOG2E, -SHIFT2));
        den[cc] += p;
        num[cc] = fmaf(msg, p, num[cc]);
    }
}

// ---------------- CSR build ----------------

// histogram + per-edge rank capture (atomic return value = edge's rank within its dst)
__global__ __launch_bounds__(256) void hist_kernel(const int* __restrict__ dst,
                                                   int* __restrict__ deg,
                                                   int* __restrict__ rank) {
    int e = blockIdx.x * 256 + threadIdx.x;
    if (e >= EE) return;
    rank[e] = atomicAdd(&deg[dst[e]], 1);
}

// block-local exclusive scan + per-block totals; also per-block degree histogram
// (bucket = 255 - clamp(deg) so high-degree nodes sort FIRST -> LPT scheduling)
__global__ __launch_bounds__(1024) void scan1_kernel(const int* __restrict__ deg,
                                                     int* __restrict__ offs,
                                                     int* __restrict__ bsum,
                                                     int* __restrict__ bhist) {
    __shared__ int ws[16];
    __shared__ int lh[256];
    int tid = threadIdx.x, lane = tid & 63, w = tid >> 6;
    if (tid < 256) lh[tid] = 0;
    int i = blockIdx.x * 1024 + tid;
    int v = (i < NN) ? deg[i] : 0;
    __syncthreads();
    if (i < NN) {
        int b = 255 - (v > 255 ? 255 : v);
        atomicAdd(&lh[b], 1);
    }
    int x = v;
    #pragma unroll
    for (int off = 1; off < 64; off <<= 1) {
        int y = __shfl_up(x, off, 64);
        if (lane >= off) x += y;
    }
    if (lane == 63) ws[w] = x;
    __syncthreads();
    int wpre = 0;
    for (int j = 0; j < w; ++j) wpre += ws[j];
    if (i < NN) offs[i] = wpre + x - v;
    if (tid == 1023) bsum[blockIdx.x] = wpre + x;
    if (tid < 256) bhist[tid * NB_SCAN + blockIdx.x] = lh[tid];
}

// merged: fast bhist exclusive scan (local-13 + one block scan) + bsum scan + pool zero
__global__ __launch_bounds__(1024) void bscan_kernel(int* __restrict__ bhist,
                                                     int* __restrict__ bsum,
                                                     float* __restrict__ pool) {
    __shared__ int ws[16];
    int tid = threadIdx.x, lane = tid & 63, w = tid >> 6;
    for (int i = tid; i < GG * HH; i += 1024) pool[i] = 0.f;
    if (tid < 64) {
        int v = (tid < NB_SCAN) ? bsum[tid] : 0;
        int x = v;
        #pragma unroll
        for (int off = 1; off < 64; off <<= 1) {
            int y = __shfl_up(x, off, 64);
            if (lane >= off) x += y;
        }
        if (tid < NB_SCAN) bsum[tid] = x - v;
    }
    int base = tid * BSCAN_PT;
    int loc[BSCAN_PT];
    int s = 0;
    #pragma unroll
    for (int i = 0; i < BSCAN_PT; ++i) {
        int idx = base + i;
        int v = (idx < NBH) ? bhist[idx] : 0;
        loc[i] = s;
        s += v;
    }
    int x = s;
    #pragma unroll
    for (int off = 1; off < 64; off <<= 1) {
        int y = __shfl_up(x, off, 64);
        if (lane >= off) x += y;
    }
    if (lane == 63) ws[w] = x;
    __syncthreads();
    int wpre = 0;
    for (int j = 0; j < w; ++j) wpre += ws[j];
    int pre = wpre + x - s;  // exclusive prefix of this thread's chunk
    #pragma unroll
    for (int i = 0; i < BSCAN_PT; ++i) {
        int idx = base + i;
        if (idx < NBH) bhist[idx] = pre + loc[i];
    }
}

// merged: offs finalize + degree-sorted permutation (no global atomics)
__global__ __launch_bounds__(1024) void finsort_kernel(int* __restrict__ offs,
                                                       const int* __restrict__ bsum,
                                                       const int* __restrict__ deg,
                                                       const int* __restrict__ bhist,
                                                       int* __restrict__ perm) {
    __shared__ int cnt[256];
    int tid = threadIdx.x;
    if (tid < 256) cnt[tid] = 0;
    __syncthreads();
    int n = blockIdx.x * 1024 + tid;
    if (n < NN) {
        offs[n] += bsum[blockIdx.x];
        int d = deg[n];
        int b = 255 - (d > 255 ? 255 : d);
        int rank = atomicAdd(&cnt[b], 1);
        perm[bhist[b * NB_SCAN + blockIdx.x] + rank] = n;
    }
    if (n == NN) offs[NN] = EE;
}

// scatter (NO atomics): 64B-slot csrea; csr_src premultiplied byte offsets
__global__ __launch_bounds__(256) void scatter_kernel(const int* __restrict__ src,
                                                      const int* __restrict__ dst,
                                                      const int* __restrict__ offs,
                                                      const int* __restrict__ rank,
                                                      const float* __restrict__ eattr,
                                                      int* __restrict__ csr_src,
                                                      float4* __restrict__ csrea) {
    int e = blockIdx.x * 256 + threadIdx.x;
    if (e >= EE) return;
    int d = dst[e];
    int slot = offs[d] + rank[e];
    csr_src[slot] = src[e] * (HH * 2);  // byte offset into f16 hidden-state array
    const float4* ep = (const float4*)(eattr + (size_t)e * EDF);
    float4 v0 = ep[0], v1 = ep[1], v2 = ep[2], v3 = ep[3];
    union { f16x2 h[4]; float4 f; } a, b;
    a.h[0] = f16x2{(f16)v0.x, (f16)v0.y};
    a.h[1] = f16x2{(f16)v0.z, (f16)v0.w};
    a.h[2] = f16x2{(f16)v1.x, (f16)v1.y};
    a.h[3] = f16x2{(f16)v1.z, (f16)v1.w};
    b.h[0] = f16x2{(f16)v2.x, (f16)v2.y};
    b.h[1] = f16x2{(f16)v2.z, (f16)v2.w};
    b.h[2] = f16x2{(f16)v3.x, (f16)v3.y};
    b.h[3] = f16x2{(f16)v3.z, (f16)v3.w};
    float4* outp = csrea + (size_t)slot * 4;
    outp[0] = a.f;
    outp[1] = b.f;
    outp[2] = float4{0.f, 0.f, 0.f, 0.f};  // pad: completes the 64B slot
    outp[3] = float4{0.f, 0.f, 0.f, 0.f};
}

// --- layer-1 projections (persistent) with FOLDED weight prep + csr pad zeroing ---

__global__ __launch_bounds__(256) void proj_kernel(
    const float* __restrict__ x, const float* __restrict__ ws, const float* __restrict__ wd,
    const float* __restrict__ we0, const float* __restrict__ we1, const float* __restrict__ we2,
    const float* __restrict__ m10, const float* __restrict__ m11, const float* __restrict__ m12,
    const float* __restrict__ m20, const float* __restrict__ m21, const float* __restrict__ m22,
    f16* __restrict__ wte, f16* __restrict__ wt1, f16* __restrict__ wt2,
    int* __restrict__ csr_src, f16* __restrict__ xs, f16* __restrict__ xd) {
    __shared__ float Ws[INF * HH], Wd[INF * HH];
    int tid = threadIdx.x;
    // folded weight prep: one item per thread (grid has 262144 threads >= 115200)
    int idx = blockIdx.x * 256 + tid;
    if (idx < 8) csr_src[EE + idx] = 0;  // pads: agg prefetch overruns gather node 0
    if (idx < 4608) {
        const float* w = (idx < 1536) ? we0 : ((idx < 3072) ? we1 : we2);
        int r = idx % 1536, c = r / EDF, k = r % EDF;
        wte[idx] = (f16)w[k * HH + c];
    } else if (idx < 4608 + 3 * 18432) {
        int m = idx - 4608;
        const float* w = (m < 18432) ? m10 : ((m < 36864) ? m11 : m12);
        int r = m % 18432, j = r / HH, k = r % HH;  // [192][96]
        wt1[m] = (f16)w[k * H2 + j];
    } else if (idx < WPREP_N) {
        int m = idx - 4608 - 3 * 18432;
        const float* w = (m < 18432) ? m20 : ((m < 36864) ? m21 : m22);
        int r = m % 18432, j = r / H2, k = r % H2;  // [96][192]
        wt2[m] = (f16)w[k * HH + j];
    }
    for (int i = tid; i < INF * HH; i += 256) { Ws[i] = ws[i]; Wd[i] = wd[i]; }
    __syncthreads();
    for (int gid = blockIdx.x * 256 + tid; gid < NN * HH; gid += PROJ_GRID * 256) {
        int n = gid / HH, c = gid % HH;
        const float* xr = x + (size_t)n * INF;
        float as = 0.f, ad = 0.f;
        #pragma unroll
        for (int k = 0; k < INF; ++k) {
            float xv = xr[k];
            as = fmaf(xv, Ws[k * HH + c], as);
            ad = fmaf(xv, Wd[k * HH + c], ad);
        }
        xs[gid] = (f16)as;
        xd[gid] = (f16)ad;
    }
}

// ---- GENConv softmax aggregation: LPT-sorted, unroll-3 rotation, 64B-slot reads ----

#define AGG_LOAD(E0, E1, XU, JJ, SO)                                     \
    E0.f = csrea[(size_t)(JJ) * 4];                                      \
    E1.f = csrea[(size_t)(JJ) * 4 + 1];                                  \
    XU.f = *(const float2*)(xsrcb + (size_t)(unsigned)(SO) + c0 * 2);

__global__ __launch_bounds__(192) void agg_kernel(const f16* __restrict__ xsrc,
                                                  const f16* __restrict__ xdst,
                                                  const float4* __restrict__ csrea,
                                                  const f16* __restrict__ wt,
                                                  const int* __restrict__ offs,
                                                  const int* __restrict__ csr_src,
                                                  const int* __restrict__ perm,
                                                  float* __restrict__ stats,
                                                  f16* __restrict__ hpre) {
    int tid = threadIdx.x;
    if (blockIdx.x == 0) {  // fold BN-stats zeroing (consumed by gemm1/gemm2 after us)
        for (int t = tid; t < 576; t += 192) stats[t] = 0.f;
    }
    int idx = blockIdx.x * 8 + tid / 24;
    if (idx >= NN) return;
    int node = perm[idx];
    int cg = tid % 24, c0 = cg * 4;
    const char* xsrcb = (const char*)xsrc;
    W8 w[4];
    #pragma unroll
    for (int cc = 0; cc < 4; ++cc) {
        const float4* wp = (const float4*)(wt + (c0 + cc) * EDF);
        w[cc].f[0] = wp[0];
        w[cc].f[1] = wp[1];
    }
    XUu xd;
    xd.f = *(const float2*)(xdst + (size_t)node * HH + c0);
    int s0 = offs[node], s1 = offs[node + 1];
    float num[4] = {0.f, 0.f, 0.f, 0.f}, den[4] = {0.f, 0.f, 0.f, 0.f};
    if (s0 < s1) {
        int last = s1 - 1;
        EAu eA0, eA1, eB0, eB1, eC0, eC1;
        XUu xA, xB, xC;
        int sA = csr_src[s0], sB = csr_src[s0 + 1], sC = csr_src[s0 + 2];
        AGG_LOAD(eA0, eA1, xA, s0, sA)
        AGG_LOAD(eB0, eB1, xB, s0 + 1, sB)
        AGG_LOAD(eC0, eC1, xC, s0 + 2, sC)
        int sD = csr_src[s0 + 3], sE = csr_src[s0 + 4], sF = csr_src[s0 + 5];
        for (int j = s0; j < s1; j += 3) {
            // slot A: compute (always valid), then reload for j+3
            __builtin_amdgcn_s_setprio(1);
            agg_step(eA0, eA1, xA, w, num, den);
            __builtin_amdgcn_s_setprio(0);
            AGG_LOAD(eA0, eA1, xA, j + 3, sD)
            sD = csr_src[j + 6];
            // slot B
            if (j + 1 <= last) {
                __builtin_amdgcn_s_setprio(1);
                agg_step(eB0, eB1, xB, w, num, den);
                __builtin_amdgcn_s_setprio(0);
            }
            AGG_LOAD(eB0, eB1, xB, j + 4, sE)
            sE = csr_src[j + 7];
            // slot C
            if (j + 2 <= last) {
                __builtin_amdgcn_s_setprio(1);
                agg_step(eC0, eC1, xC, w, num, den);
                __builtin_amdgcn_s_setprio(0);
            }
            AGG_LOAD(eC0, eC1, xC, j + 5, sF)
            sF = csr_src[j + 8];
        }
    }
    float xdv[4] = {(float)xd.h[0].x, (float)xd.h[0].y, (float)xd.h[1].x, (float)xd.h[1].y};
    float r0 = (den[0] > 0.f) ? num[0] / den[0] : 0.f;
    float r1 = (den[1] > 0.f) ? num[1] / den[1] : 0.f;
    float r2 = (den[2] > 0.f) ? num[2] / den[2] : 0.f;
    float r3 = (den[3] > 0.f) ? num[3] / den[3] : 0.f;
    union { float2 f; f16x2 h[2]; } o;
    o.h[0] = f16x2{(f16)(r0 + xdv[0]), (f16)(r1 + xdv[1])};
    o.h[1] = f16x2{(f16)(r2 + xdv[2]), (f16)(r3 + xdv[3])};
    *(float2*)(hpre + (size_t)node * HH + c0) = o.f;
}

// -- gemm1 (MFMA, persistent): T = HP @ mw1; stats in REGISTERS, one reduce at end --
#define LDA1 104  // f16 units, 16B-aligned rows, breaks bank aliasing

__global__ __launch_bounds__(256) void gemm1_kernel(const f16* __restrict__ A,
                                                    const f16* __restrict__ Wt,
                                                    f16* __restrict__ T,
                                                    float* __restrict__ colsum,
                                                    float* __restrict__ colsumsq) {
    __shared__ f16 Al[64 * LDA1];
    __shared__ f16 Wl[192 * LDA1];
    __shared__ float red[H2 * 2];
    int tid = threadIdx.x;
    for (int v = tid; v < 192 * 12; v += 256) {
        int r = v / 12, c8 = (v % 12) * 8;
        *(float4*)(Wl + r * LDA1 + c8) = *(const float4*)(Wt + r * HH + c8);
    }
    for (int t = tid; t < H2 * 2; t += 256) red[t] = 0.f;
    __syncthreads();
    int wv = tid >> 6, l = tid & 63, lr = l & 15, lg = l >> 4;
    int i0 = wv * 16;
    float sa[12], qa[12];
    #pragma unroll
    for (int t = 0; t < 12; ++t) { sa[t] = 0.f; qa[t] = 0.f; }
    for (int tile = blockIdx.x; tile < NT64; tile += GRIDP) {
        int n0 = tile * 64;
        for (int v = tid; v < 64 * 12; v += 256) {
            int r = v / 12, c8 = (v % 12) * 8;
            float4 d = {0.f, 0.f, 0.f, 0.f};
            if (n0 + r < NN) d = *(const float4*)(A + (size_t)(n0 + r) * HH + c8);
            *(float4*)(Al + r * LDA1 + c8) = d;
        }
        __syncthreads();
        f32x4 acc[12];
        #pragma unroll
        for (int t = 0; t < 12; ++t) acc[t] = (f32x4){0.f, 0.f, 0.f, 0.f};
        #pragma unroll
        for (int ks = 0; ks < 3; ++ks) {
            int k0 = ks * 32 + lg * 8;
            f16x8 af = *(const f16x8*)(Al + (i0 + lr) * LDA1 + k0);
            #pragma unroll
            for (int t = 0; t < 12; ++t) {
                f16x8 bf = *(const f16x8*)(Wl + (t * 16 + lr) * LDA1 + k0);
                acc[t] = __builtin_amdgcn_mfma_f32_16x16x32_f16(af, bf, acc[t], 0, 0, 0);
            }
        }
        #pragma unroll
        for (int t = 0; t < 12; ++t) {
            int col = t * 16 + lr;
            #pragma unroll
            for (int rr = 0; rr < 4; ++rr) {
                int row = n0 + i0 + lg * 4 + rr;
                float v = acc[t][rr];
                if (row < NN) {
                    T[(size_t)row * H2 + col] = (f16)v;
                    sa[t] += v;
                    qa[t] = fmaf(v, v, qa[t]);
                }
            }
        }
        __syncthreads();  // Al free before next stage
    }
    // one stats reduction per block
    #pragma unroll
    for (int t = 0; t < 12; ++t) {
        float s = sa[t], q = qa[t];
        s += __shfl_xor(s, 16); s += __shfl_xor(s, 32);
        q += __shfl_xor(q, 16); q += __shfl_xor(q, 32);
        if (lg == 0) { atomicAdd(&red[t * 16 + lr], s); atomicAdd(&red[H2 + t * 16 + lr], q); }
    }
    __syncthreads();
    if (tid < H2) {
        atomicAdd(&colsum[tid], red[tid]);
        atomicAdd(&colsumsq[tid], red[H2 + tid]);
    }
}

// -- gemm2 (MFMA, persistent): U = relu(bn1(T)) @ mw2, BN fused; reg stats --
#define LDA2 200

__global__ __launch_bounds__(256) void gemm2_kernel(const f16* __restrict__ T,
                                                    const f16* __restrict__ Wt,
                                                    const float* __restrict__ cs1,
                                                    const float* __restrict__ cq1,
                                                    const float* __restrict__ g1,
                                                    const float* __restrict__ b1,
                                                    f16* __restrict__ U,
                                                    float* __restrict__ colsum,
                                                    float* __restrict__ colsumsq) {
    __shared__ f16 Al[64 * LDA2];
    __shared__ f16 Wl[96 * LDA2];
    __shared__ float ab[H2 * 2];
    __shared__ float red[HH * 2];
    int tid = threadIdx.x;
    if (tid < H2) {
        const float invN = 1.f / (float)NN;
        float mu = cs1[tid] * invN;
        float var = fmaxf(cq1[tid] * invN - mu * mu, 0.f);
        float a = g1[tid] * rsqrtf(var + EPS_BN);
        ab[tid] = a;
        ab[H2 + tid] = b1[tid] - mu * a;
    }
    if (tid < HH * 2) red[tid] = 0.f;
    for (int v = tid; v < 96 * 24; v += 256) {
        int r = v / 24, c8 = (v % 24) * 8;
        *(float4*)(Wl + r * LDA2 + c8) = *(const float4*)(Wt + r * H2 + c8);
    }
    __syncthreads();
    int wv = tid >> 6, l = tid & 63, lr = l & 15, lg = l >> 4;
    int i0 = wv * 16;
    float sa[6], qa[6];
    #pragma unroll
    for (int t = 0; t < 6; ++t) { sa[t] = 0.f; qa[t] = 0.f; }
    for (int tile = blockIdx.x; tile < NT64; tile += GRIDP) {
        int n0 = tile * 64;
        for (int v = tid; v < 64 * 24; v += 256) {
            int r = v / 24, c8 = (v % 24) * 8;
            float4 dd = {0.f, 0.f, 0.f, 0.f};
            if (n0 + r < NN) {
                union { float4 f; f16x2 h[4]; } u, o;
                u.f = *(const float4*)(T + (size_t)(n0 + r) * H2 + c8);
                #pragma unroll
                for (int p = 0; p < 4; ++p) {
                    float x0 = fmaxf(fmaf((float)u.h[p].x, ab[c8 + 2 * p], ab[H2 + c8 + 2 * p]), 0.f);
                    float x1 = fmaxf(fmaf((float)u.h[p].y, ab[c8 + 2 * p + 1], ab[H2 + c8 + 2 * p + 1]), 0.f);
                    o.h[p] = f16x2{(f16)x0, (f16)x1};
                }
                dd = o.f;
            }
            *(float4*)(Al + r * LDA2 + c8) = dd;
        }
        __syncthreads();
        f32x4 acc[6];
        #pragma unroll
        for (int t = 0; t < 6; ++t) acc[t] = (f32x4){0.f, 0.f, 0.f, 0.f};
        #pragma unroll
        for (int ks = 0; ks < 6; ++ks) {
            int k0 = ks * 32 + lg * 8;
            f16x8 af = *(const f16x8*)(Al + (i0 + lr) * LDA2 + k0);
            #pragma unroll
            for (int t = 0; t < 6; ++t) {
                f16x8 bf = *(const f16x8*)(Wl + (t * 16 + lr) * LDA2 + k0);
                acc[t] = __builtin_amdgcn_mfma_f32_16x16x32_f16(af, bf, acc[t], 0, 0, 0);
            }
        }
        #pragma unroll
        for (int t = 0; t < 6; ++t) {
            int col = t * 16 + lr;
            #pragma unroll
            for (int rr = 0; rr < 4; ++rr) {
                int row = n0 + i0 + lg * 4 + rr;
                float v = acc[t][rr];
                if (row < NN) {
                    U[(size_t)row * HH + col] = (f16)v;
                    sa[t] += v;
                    qa[t] = fmaf(v, v, qa[t]);
                }
            }
        }
        __syncthreads();
    }
    #pragma unroll
    for (int t = 0; t < 6; ++t) {
        float s = sa[t], q = qa[t];
        s += __shfl_xor(s, 16); s += __shfl_xor(s, 32);
        q += __shfl_xor(q, 16); q += __shfl_xor(q, 32);
        if (lg == 0) { atomicAdd(&red[t * 16 + lr], s); atomicAdd(&red[HH + t * 16 + lr], q); }
    }
    __syncthreads();
    if (tid < HH) {
        atomicAdd(&colsum[tid], red[tid]);
        atomicAdd(&colsumsq[tid], red[HH + tid]);
    }
}

// ---------------- h = relu(bn_out(u)), BN finalize fused ----------------

__global__ __launch_bounds__(256) void elem_kernel(const f16* __restrict__ U,
                                                   const float* __restrict__ cs2,
                                                   const float* __restrict__ cq2,
                                                   const float* __restrict__ g2,
                                                   const float* __restrict__ b2,
                                                   f16* __restrict__ Hout) {
    __shared__ float ab[HH * 2];
    int tid = threadIdx.x;
    if (tid < HH) {
        const float invN = 1.f / (float)NN;
        float mu = cs2[tid] * invN;
        float var = fmaxf(cq2[tid] * invN - mu * mu, 0.f);
        float a = g2[tid] * rsqrtf(var + EPS_BN);
        ab[tid] = a;
        ab[HH + tid] = b2[tid] - mu * a;
    }
    __syncthreads();
    int i = blockIdx.x * 256 + tid;
    if (i >= NN * HH / 8) return;
    union { float4 f; f16x2 h[4]; } u, o;
    u.f = ((const float4*)U)[i];
    int k = (i % 12) * 8;
    #pragma unroll
    for (int p = 0; p < 4; ++p) {
        float x0 = fmaxf(fmaf((float)u.h[p].x, ab[k + 2 * p], ab[HH + k + 2 * p]), 0.f);
        float x1 = fmaxf(fmaf((float)u.h[p].y, ab[k + 2 * p + 1], ab[HH + k + 2 * p + 1]), 0.f);
        o.h[p] = f16x2{(f16)x0, (f16)x1};
    }
    ((float4*)Hout)[i] = o.f;
}

// ------- mean-pool with fused final BN+relu (last layer), segmented accumulation -------

__global__ __launch_bounds__(192) void pool_bn_kernel(const f16* __restrict__ U,
                                                      const float* __restrict__ cs2,
                                                      const float* __restrict__ cq2,
                                                      const float* __restrict__ g2,
                                                      const float* __restrict__ b2,
                                                      const int* __restrict__ batch,
                                                      float* __restrict__ pool) {
    __shared__ float ab[HH * 2];
    int tid = threadIdx.x;
    if (tid < HH) {
        const float invN = 1.f / (float)NN;
        float mu = cs2[tid] * invN;
        float var = fmaxf(cq2[tid] * invN - mu * mu, 0.f);
        float a = g2[tid] * rsqrtf(var + EPS_BN);
        ab[tid] = a;
        ab[HH + tid] = b2[tid] - mu * a;
    }
    __syncthreads();
    int n0 = blockIdx.x * NPB;
    int n1 = (n0 + NPB < NN) ? n0 + NPB : NN;
    int c = tid % HH;
    int h = tid / HH;
    float a_ = ab[c], b_ = ab[HH + c];
    float acc = 0.f;
    int gcur = -1;
    for (int n = n0 + h; n < n1; n += 2) {
        int g = batch[n];
        if (g != gcur) {
            if (gcur >= 0) atomicAdd(&pool[gcur * HH + c], acc);
            acc = 0.f;
            gcur = g;
        }
        acc += fmaxf(fmaf((float)U[(size_t)n * HH + c], a_, b_), 0.f);
    }
    if (gcur >= 0) atomicAdd(&pool[gcur * HH + c], acc);
}

// final linear; per-graph count via binary search (fused, uniform per block)
__global__ __launch_bounds__(128) void out_kernel(const float* __restrict__ pool,
                                                  const int* __restrict__ batch,
                                                  const float* __restrict__ lw,
                                                  const float* __restrict__ lb,
                                                  float* __restrict__ out) {
    int g = blockIdx.x, o = threadIdx.x;
    int lo = 0, hi = NN;
    while (lo < hi) { int mid = (lo + hi) >> 1; if (batch[mid] < g) lo = mid + 1; else hi = mid; }
    int s = lo;
    lo = 0; hi = NN;
    while (lo < hi) { int mid = (lo + hi) >> 1; if (batch[mid] < g + 1) lo = mid + 1; else hi = mid; }
    float inv = 1.f / fmaxf((float)(lo - s), 1.f);
    float acc = lb[o];
    for (int c = 0; c < HH; ++c) acc = fmaf(pool[g * HH + c] * inv, lw[c * OUTF + o], acc);
    out[(size_t)g * OUTF + o] = acc;
}

// ---------------- host ----------------

extern "C" void kernel_launch(void* const* d_in, const int* in_sizes, int n_in,
                              void* d_out, int out_size, void* d_ws, size_t ws_size,
                              hipStream_t stream) {
    const float* x = (const float*)d_in[0];
    const float* eattr = (const float*)d_in[1];
    const int* eidx = (const int*)d_in[2];
    const int* batch = (const int*)d_in[3];
    const float* w_src1 = (const float*)d_in[4];
    const float* w_dst1 = (const float*)d_in[5];
    const float* w_e[3] = {(const float*)d_in[6], (const float*)d_in[13], (const float*)d_in[20]};
    const float* mw1[3] = {(const float*)d_in[7], (const float*)d_in[14], (const float*)d_in[21]};
    const float* mg[3] = {(const float*)d_in[8], (const float*)d_in[15], (const float*)d_in[22]};
    const float* mb[3] = {(const float*)d_in[9], (const float*)d_in[16], (const float*)d_in[23]};
    const float* mw2[3] = {(const float*)d_in[10], (const float*)d_in[17], (const float*)d_in[24]};
    const float* bng[3] = {(const float*)d_in[11], (const float*)d_in[18], (const float*)d_in[25]};
    const float* bnb[3] = {(const float*)d_in[12], (const float*)d_in[19], (const float*)d_in[26]};
    const float* lin_w = (const float*)d_in[27];
    const float* lin_b = (const float*)d_in[28];
    float* out = (float*)d_out;

    const int* src = eidx;
    const int* dst = eidx + EE;

    // ---- workspace layout ----
    char* base = (char*)d_ws;
    size_t off = 0;
    int* deg = (int*)(base + off); off = align256(off + (size_t)NN * 4);
    int* offs = (int*)(base + off); off = align256(off + (size_t)(NN + 1) * 4);
    int* bsum = (int*)(base + off); off = align256(off + (size_t)NB_SCAN * 4);
    int* bhist = (int*)(base + off); off = align256(off + (size_t)NBH * 4);
    int* perm = (int*)(base + off); off = align256(off + (size_t)NN * 4);
    int* csr_src = (int*)(base + off); off = align256(off + (size_t)(EE + 8) * 4);
    float* stats = (float*)(base + off); off = align256(off + 576 * 4);
    float* colsum1 = stats;            // 192
    float* colsumsq1 = stats + 192;    // 192
    float* colsum2 = stats + 384;      // 96
    float* colsumsq2 = stats + 480;    // 96
    float* pool = (float*)(base + off); off = align256(off + (size_t)GG * HH * 4);
    f16* wte = (f16*)(base + off); off = align256(off + (size_t)3 * 1536 * 2);
    f16* wt1 = (f16*)(base + off); off = align256(off + (size_t)3 * 18432 * 2);
    f16* wt2 = (f16*)(base + off); off = align256(off + (size_t)3 * 18432 * 2);
    f16* XS = (f16*)(base + off); off = align256(off + (size_t)NN * HH * 2);   // xs -> h
    f16* XD = (f16*)(base + off); off = align256(off + (size_t)NN * HH * 2);   // xd (layer1)
    f16* HP = (f16*)(base + off); off = align256(off + (size_t)NN * HH * 2);   // hpre -> U
    f16* T = (f16*)(base + off); off = align256(off + (size_t)NN * H2 * 2);
    float4* csrea = (float4*)(base + off); off = align256(off + (size_t)(EE + 8) * 64);
    int* rank = (int*)T;  // aliased: rank dead before first T write (gemm1 layer 0)
    (void)in_sizes; (void)n_in; (void)out_size; (void)ws_size;

    // ---- CSR build + LPT degree sort (atomic-free scatter via rank capture) ----
    hipMemsetAsync(deg, 0, (size_t)NN * 4, stream);
    hist_kernel<<<(EE + 255) / 256, 256, 0, stream>>>(dst, deg, rank);
    scan1_kernel<<<NB_SCAN, 1024, 0, stream>>>(deg, offs, bsum, bhist);
    bscan_kernel<<<1, 1024, 0, stream>>>(bhist, bsum, pool);
    finsort_kernel<<<NB_SCAN, 1024, 0, stream>>>(offs, bsum, deg, bhist, perm);
    scatter_kernel<<<(EE + 255) / 256, 256, 0, stream>>>(src, dst, offs, rank, eattr,
                                                         csr_src, csrea);
    proj_kernel<<<PROJ_GRID, 256, 0, stream>>>(
        x, w_src1, w_dst1, w_e[0], w_e[1], w_e[2], mw1[0], mw1[1], mw1[2],
        mw2[0], mw2[1], mw2[2], wte, wt1, wt2, csr_src, XS, XD);

    // ---- 3 GENConv layers ----
    for (int l = 0; l < 3; ++l) {
        const f16* xdst = (l == 0) ? XD : XS;
        agg_kernel<<<(NN + 7) / 8, 192, 0, stream>>>(XS, xdst, csrea, wte + l * 1536, offs,
                                                     csr_src, perm, stats, HP);
        gemm1_kernel<<<GRIDP, 256, 0, stream>>>(HP, wt1 + l * 18432, T, colsum1, colsumsq1);
        gemm2_kernel<<<GRIDP, 256, 0, stream>>>(T, wt2 + l * 18432, colsum1, colsumsq1,
                                                mg[l], mb[l], HP, colsum2, colsumsq2);
        if (l < 2)
            elem_kernel<<<(NN * HH / 8 + 255) / 256, 256, 0, stream>>>(HP, colsum2, colsumsq2,
                                                                       bng[l], bnb[l], XS);
    }

    // ---- pooling (fused layer-3 BN+relu; pool zeroed in bscan) + final linear ----
    pool_bn_kernel<<<(NN + NPB - 1) / NPB, 192, 0, stream>>>(HP, colsum2, colsumsq2,
                                                             bng[2], bnb[2], batch, pool);
    out_kernel<<<GG, 128, 0, stream>>>(pool, batch, lin_w, lin_b, out);
}